// Round 1
// 16221.622 us; speedup vs baseline: 1.3898x; 1.3898x over previous
//
#include <hip/hip_runtime.h>
#include <hip/hip_fp16.h>
#include <stdint.h>

// LSTM_29042568856007: B=64, T=4096, D=256, H=256.
// Round 5: kill the L2 weight stream. W_hh f16 = 512 KB/WG, split:
//   k4  0..15 -> VGPRs   (64 regs/thread; __launch_bounds__(1024,4) => 128-reg cap.
//                         Round 3 spilled because default cap was 64.)
//   k4 16..23 -> LDS     (128 KiB; freed by deleting the pointless xg_s round-trip)
//   k4 24..31 -> L2 stream (128 KB/step, issued early, hidden by 4-wave TLP)
// Per-CU L2 traffic per step: 576 KB -> 136 KB (4.2x). VALU dots become the floor.

#define LSTM_B 64
#define LSTM_T 4096
#define LSTM_D 256
#define LSTM_H 256
#define NX 8
#define NG (LSTM_T / NX)

typedef __attribute__((ext_vector_type(2))) _Float16 half2_t;

static __device__ __forceinline__ float dot2(uint32_t w, uint32_t a, float acc) {
#if __has_builtin(__builtin_amdgcn_fdot2)
    return __builtin_amdgcn_fdot2(__builtin_bit_cast(half2_t, w),
                                  __builtin_bit_cast(half2_t, a), acc, false);
#else
    __half2 hw = __builtin_bit_cast(__half2, w);
    __half2 ha = __builtin_bit_cast(__half2, a);
    acc = fmaf(__low2float(hw), __low2float(ha), acc);
    acc = fmaf(__high2float(hw), __high2float(ha), acc);
    return acc;
#endif
}

// ws: uint4 Wp[64][1024] (k4, r), 1 MiB packed f16 pairs.
//   k4 in [0,32): W_ih; k4 in [32,64): W_hh.
__global__ __launch_bounds__(256) void prep_weights(
    const float* __restrict__ W_ih, const float* __restrict__ W_hh,
    uint32_t* __restrict__ Wp)
{
    int idx = blockIdx.x * blockDim.x + threadIdx.x;  // [0, 262144)
    if (idx >= 64 * 1024 * 4) return;
    int e  = idx & 3;
    int r  = (idx >> 2) & 1023;
    int k4 = idx >> 12;
    int k  = ((k4 & 31) << 3) + (e << 1);
    const float* W = (k4 < 32) ? W_ih : W_hh;
    uint32_t lo = (uint32_t)__half_as_ushort(__float2half(W[r * 256 + k]));
    uint32_t hi = (uint32_t)__half_as_ushort(__float2half(W[r * 256 + k + 1]));
    Wp[idx] = lo | (hi << 16);
}

static __device__ __forceinline__ float sigmoidf_(float x) {
    return 1.0f / (1.0f + __expf(-x));
}
static __device__ __forceinline__ float tanhf_(float x) {
    float ax = fabsf(x);
    float e  = __expf(-2.0f * ax);
    float t  = (1.0f - e) / (1.0f + e);
    return copysignf(t, x);
}

#define DOT4(wv, hv) do { \
    acc0 = dot2((wv).x, (hv).x, acc0); \
    acc1 = dot2((wv).y, (hv).y, acc1); \
    acc0 = dot2((wv).z, (hv).z, acc0); \
    acc1 = dot2((wv).w, (hv).w, acc1); } while (0)

__global__ __launch_bounds__(1024, 4) void lstm_r5(
    const float* __restrict__ xs,     // [B, T, D] fp32
    const float* __restrict__ bias_g, // [4H]
    const uint4* __restrict__ Wp,     // [64][1024] f16-pair octets
    float* __restrict__ out)          // h[B,H] then c[B,H]
{
    __shared__ __align__(16) uint4    wlds[8 * 1024];  // 128 KiB: W_hh k4=16..23, [j][r]
    __shared__ __align__(16) uint32_t x_u[NX * 128];   // 4 KiB  (f16-packed x, 8 steps)
    __shared__ __align__(16) uint32_t h_u[128];        // 512 B  (f16-packed h)
    __shared__ __align__(16) float    g_s[1024];       // 4 KiB  (gate values)

    const int tid = threadIdx.x;   // gate row r = tid
    const int b   = blockIdx.x;    // batch element

    const float bias = bias_g[tid];
    const float* xrow = xs + (size_t)b * LSTM_T * LSTM_D;

    const uint4* Wih = Wp + tid;               // + (k4<<10), k4 in [0,32)
    const uint4* Whr = Wp + (32 << 10) + tid;  // W_hh reg region    (k4 0..15)
    const uint4* Whs = Wp + (56 << 10) + tid;  // W_hh stream region (k4 24..31)
    const uint4* x_u4 = (const uint4*)x_u;
    const uint4* h_u4 = (const uint4*)h_u;

    // ---- one-time: W_hh k4=0..15 into registers (64 VGPRs) ----
    uint4 wreg[16];
    #pragma unroll
    for (int j = 0; j < 16; ++j) wreg[j] = Whr[j << 10];

    // ---- one-time: W_hh k4=16..23 into LDS (128 KiB) ----
    #pragma unroll
    for (int j = 0; j < 8; ++j)
        wlds[(j << 10) + tid] = Wp[((48 + j) << 10) + tid];

    if (tid < 128) h_u[tid] = 0u;
    float c = 0.0f, hlast = 0.0f;

    // prefetch group 0's x: 8 steps * 256 floats = 1024 float2, one per thread
    float2 xpre = ((const float2*)xrow)[tid];

    for (int tg = 0; tg < NG; ++tg) {
        // ---- stage packed-f16 x for this group; prefetch next group ----
        {
            __half2 p = __floats2half2_rn(xpre.x, xpre.y);
            x_u[tid] = __builtin_bit_cast(uint32_t, p);  // tid = tt*128 + kpair
            int ng = (tg + 1 < NG) ? tg + 1 : tg;
            xpre = ((const float2*)(xrow + (size_t)ng * NX * LSTM_D))[tid];
        }
        __syncthreads();   // bar 1: x_u ready (also covers wlds/h_u init on tg=0)

        // ---- x-pass: xacc[tt] = bias + W_ih[tid,:].x_t  (stays in registers) ----
        float xacc[NX];
        #pragma unroll
        for (int tt = 0; tt < NX; ++tt) xacc[tt] = bias;
        #pragma unroll 2
        for (int k4 = 0; k4 < 32; ++k4) {
            uint4 w = Wih[k4 << 10];
            #pragma unroll
            for (int tt = 0; tt < NX; ++tt) {
                uint4 xa = x_u4[tt * 32 + k4];   // wave-uniform -> broadcast
                float s = xacc[tt];
                s = dot2(w.x, xa.x, s);
                s = dot2(w.y, xa.y, s);
                s = dot2(w.z, xa.z, s);
                s = dot2(w.w, xa.w, s);
                xacc[tt] = s;
            }
        }
        // no barrier: xacc is register-private; x_u not rewritten until after bar H

        // ---- NX recurrence steps ----
        #pragma unroll 1
        for (int tt = 0; tt < NX; ++tt) {
            // issue first half of streamed W_hh early (k4=24..27)
            uint4 ws0 = Whs[0 << 10];
            uint4 ws1 = Whs[1 << 10];
            uint4 ws2 = Whs[2 << 10];
            uint4 ws3 = Whs[3 << 10];

            float acc0 = xacc[tt];
            float acc1 = 0.0f;

            // register-resident W_hh: k4 = 0..15
            #pragma unroll
            for (int k4 = 0; k4 < 16; ++k4) {
                uint4 ha = h_u4[k4];             // wave-uniform -> broadcast
                DOT4(wreg[k4], ha);
            }

            // LDS-resident W_hh: k4 = 16..23
            #pragma unroll
            for (int j = 0; j < 8; ++j) {
                uint4 w  = wlds[(j << 10) + tid];  // lane-consecutive b128, conflict-free
                uint4 ha = h_u4[16 + j];
                DOT4(w, ha);
            }

            // second half of streamed loads (k4=28..31)
            uint4 ws4 = Whs[4 << 10];
            uint4 ws5 = Whs[5 << 10];
            uint4 ws6 = Whs[6 << 10];
            uint4 ws7 = Whs[7 << 10];

            { uint4 ha = h_u4[24]; DOT4(ws0, ha); }
            { uint4 ha = h_u4[25]; DOT4(ws1, ha); }
            { uint4 ha = h_u4[26]; DOT4(ws2, ha); }
            { uint4 ha = h_u4[27]; DOT4(ws3, ha); }
            { uint4 ha = h_u4[28]; DOT4(ws4, ha); }
            { uint4 ha = h_u4[29]; DOT4(ws5, ha); }
            { uint4 ha = h_u4[30]; DOT4(ws6, ha); }
            { uint4 ha = h_u4[31]; DOT4(ws7, ha); }

            g_s[tid] = acc0 + acc1;
            __syncthreads();   // bar G: gates ready

            if (tid < LSTM_H) {
                float gi = g_s[tid];
                float gf = g_s[tid + 256];
                float gg = g_s[tid + 512];
                float go = g_s[tid + 768];
                c = sigmoidf_(gf) * c + sigmoidf_(gi) * tanhf_(gg);
                hlast = sigmoidf_(go) * tanhf_(c);
                // pack h into f16 pairs: even lane combines with odd partner
                uint32_t mine = (uint32_t)__half_as_ushort(__float2half(hlast));
                uint32_t partner = (uint32_t)__shfl_xor((int)mine, 1, 64);
                if ((tid & 1) == 0) h_u[tid >> 1] = (mine & 0xffffu) | (partner << 16);
            }
            __syncthreads();   // bar H: h_{t+1} visible for next dot
        }
    }

    if (tid < LSTM_H) {
        out[b * LSTM_H + tid]                   = hlast;  // h_T
        out[LSTM_B * LSTM_H + b * LSTM_H + tid] = c;      // c_T
    }
}

extern "C" void kernel_launch(void* const* d_in, const int* in_sizes, int n_in,
                              void* d_out, int out_size, void* d_ws, size_t ws_size,
                              hipStream_t stream) {
    const float* xs   = (const float*)d_in[0];  // [64,4096,256]
    const float* W_ih = (const float*)d_in[1];  // [1024,256]
    const float* W_hh = (const float*)d_in[2];  // [1024,256]
    const float* b    = (const float*)d_in[3];  // [1024]
    float* out = (float*)d_out;
    uint32_t* Wp = (uint32_t*)d_ws;             // 1 MiB packed f16 weights

    prep_weights<<<1024, 256, 0, stream>>>(W_ih, W_hh, Wp);
    lstm_r5<<<LSTM_B, 1024, 0, stream>>>(xs, b, (const uint4*)Wp, out);
}

// Round 2
// 15979.131 us; speedup vs baseline: 1.4108x; 1.0152x over previous
//
#include <hip/hip_runtime.h>
#include <hip/hip_fp16.h>
#include <stdint.h>

// LSTM_29042568856007: B=64, T=4096, D=256, H=256.
// Round 6: r5's "register-resident W_hh" silently failed — VGPR_Count=64 proves
// the allocator REMATERIALIZED the wreg loads inside the step loop (64 regs is
// wreg alone; budget stayed 64 despite __launch_bounds__(1024,4)). Per-CU L2
// stream was still ~100 GB/s = the step time. Fixes:
//   (a) amdgpu_waves_per_eu(4,4): pin budget to 128 VGPR/lane.
//   (b) opacity pin via asm("" : "+v") on every wreg component -> loads cannot
//       be rematerialized; allocator must keep them live (fits: ~115/128).
//   (c) one more k4 moved stream->LDS: LDS W_hh 8->9 k4 (144 KiB, total 152.5).
// W_hh residency: k4 0..15 VGPR (64 regs), 16..24 LDS, 25..31 L2 stream.
// Per-step L2 traffic: 392 KB -> 120 KB. Target: VALU/dot2-bound step.

#define LSTM_B 64
#define LSTM_T 4096
#define LSTM_D 256
#define LSTM_H 256
#define NX 8
#define NG (LSTM_T / NX)
#define NREG 16
#define NLDS 9
#define NSTR 7

typedef __attribute__((ext_vector_type(2))) _Float16 half2_t;

static __device__ __forceinline__ float dot2(uint32_t w, uint32_t a, float acc) {
#if __has_builtin(__builtin_amdgcn_fdot2)
    return __builtin_amdgcn_fdot2(__builtin_bit_cast(half2_t, w),
                                  __builtin_bit_cast(half2_t, a), acc, false);
#else
    __half2 hw = __builtin_bit_cast(__half2, w);
    __half2 ha = __builtin_bit_cast(__half2, a);
    acc = fmaf(__low2float(hw), __low2float(ha), acc);
    acc = fmaf(__high2float(hw), __high2float(ha), acc);
    return acc;
#endif
}

// ws: uint4 Wp[64][1024] (k4, r), 1 MiB packed f16 pairs.
//   k4 in [0,32): W_ih; k4 in [32,64): W_hh.
__global__ __launch_bounds__(256) void prep_weights(
    const float* __restrict__ W_ih, const float* __restrict__ W_hh,
    uint32_t* __restrict__ Wp)
{
    int idx = blockIdx.x * blockDim.x + threadIdx.x;  // [0, 262144)
    if (idx >= 64 * 1024 * 4) return;
    int e  = idx & 3;
    int r  = (idx >> 2) & 1023;
    int k4 = idx >> 12;
    int k  = ((k4 & 31) << 3) + (e << 1);
    const float* W = (k4 < 32) ? W_ih : W_hh;
    uint32_t lo = (uint32_t)__half_as_ushort(__float2half(W[r * 256 + k]));
    uint32_t hi = (uint32_t)__half_as_ushort(__float2half(W[r * 256 + k + 1]));
    Wp[idx] = lo | (hi << 16);
}

static __device__ __forceinline__ float sigmoidf_(float x) {
    return 1.0f / (1.0f + __expf(-x));
}
static __device__ __forceinline__ float tanhf_(float x) {
    float ax = fabsf(x);
    float e  = __expf(-2.0f * ax);
    float t  = (1.0f - e) / (1.0f + e);
    return copysignf(t, x);
}

#define DOT4(wv, hv) do { \
    acc0 = dot2((wv).x, (hv).x, acc0); \
    acc1 = dot2((wv).y, (hv).y, acc1); \
    acc0 = dot2((wv).z, (hv).z, acc0); \
    acc1 = dot2((wv).w, (hv).w, acc1); } while (0)

__global__ __attribute__((amdgpu_flat_work_group_size(1024, 1024),
                          amdgpu_waves_per_eu(4, 4)))
void lstm_r6(
    const float* __restrict__ xs,     // [B, T, D] fp32
    const float* __restrict__ bias_g, // [4H]
    const uint4* __restrict__ Wp,     // [64][1024] f16-pair octets
    float* __restrict__ out)          // h[B,H] then c[B,H]
{
    __shared__ __align__(16) uint4    wlds[NLDS * 1024]; // 144 KiB: W_hh k4=16..24
    __shared__ __align__(16) uint32_t x_u[NX * 128];     // 4 KiB (f16-packed x)
    __shared__ __align__(16) uint32_t h_u[128];          // 512 B (f16-packed h)
    __shared__ __align__(16) float    g_s[1024];         // 4 KiB (gate values)

    const int tid = threadIdx.x;   // gate row r = tid
    const int b   = blockIdx.x;    // batch element

    const float bias = bias_g[tid];
    const float* xrow = xs + (size_t)b * LSTM_T * LSTM_D;

    const uint4* Wih = Wp + tid;                            // k4 in [0,32)
    const uint4* Whr = Wp + (32 << 10) + tid;               // W_hh reg    k4 0..15
    const uint4* Whl = Wp + ((32 + NREG) << 10) + tid;      // W_hh LDS    k4 16..24
    const uint4* Whs = Wp + ((32 + NREG + NLDS) << 10) + tid; // W_hh stream k4 25..31
    const uint4* x_u4 = (const uint4*)x_u;
    const uint4* h_u4 = (const uint4*)h_u;

    // ---- one-time: W_hh k4=0..15 into registers (64 VGPRs) ----
    uint4 wreg[NREG];
    #pragma unroll
    for (int j = 0; j < NREG; ++j) wreg[j] = Whr[j << 10];
    // Opacity pin: values can no longer be rematerialized from their loads,
    // so the allocator must keep them live in VGPRs (budget = 128 via
    // waves_per_eu(4,4)) instead of re-streaming 256 KB/step from L2.
    #pragma unroll
    for (int j = 0; j < NREG; ++j) {
        asm volatile("" : "+v"(wreg[j].x), "+v"(wreg[j].y),
                          "+v"(wreg[j].z), "+v"(wreg[j].w));
    }

    // ---- one-time: W_hh k4=16..24 into LDS (144 KiB) ----
    #pragma unroll
    for (int j = 0; j < NLDS; ++j)
        wlds[(j << 10) + tid] = Whl[j << 10];

    if (tid < 128) h_u[tid] = 0u;
    float c = 0.0f, hlast = 0.0f;

    // prefetch group 0's x: 8 steps * 256 floats = 1024 float2, one per thread
    float2 xpre = ((const float2*)xrow)[tid];

    for (int tg = 0; tg < NG; ++tg) {
        // ---- stage packed-f16 x for this group; prefetch next group ----
        {
            __half2 p = __floats2half2_rn(xpre.x, xpre.y);
            x_u[tid] = __builtin_bit_cast(uint32_t, p);  // tid = tt*128 + kpair
            int ng = (tg + 1 < NG) ? tg + 1 : tg;
            xpre = ((const float2*)(xrow + (size_t)ng * NX * LSTM_D))[tid];
        }
        __syncthreads();   // bar 1: x_u ready (also covers wlds/h_u init on tg=0)

        // ---- x-pass: xacc[tt] = bias + W_ih[tid,:].x_t  (stays in registers) ----
        float xacc[NX];
        #pragma unroll
        for (int tt = 0; tt < NX; ++tt) xacc[tt] = bias;
        #pragma unroll 2
        for (int k4 = 0; k4 < 32; ++k4) {
            uint4 w = Wih[k4 << 10];
            #pragma unroll
            for (int tt = 0; tt < NX; ++tt) {
                uint4 xa = x_u4[tt * 32 + k4];   // wave-uniform -> broadcast
                float s = xacc[tt];
                s = dot2(w.x, xa.x, s);
                s = dot2(w.y, xa.y, s);
                s = dot2(w.z, xa.z, s);
                s = dot2(w.w, xa.w, s);
                xacc[tt] = s;
            }
        }
        // no barrier: xacc is register-private; x_u not rewritten until after bar H

        // ---- NX recurrence steps ----
        #pragma unroll 1
        for (int tt = 0; tt < NX; ++tt) {
            // issue first chunk of streamed W_hh early (k4=25..28)
            uint4 ws0 = Whs[0 << 10];
            uint4 ws1 = Whs[1 << 10];
            uint4 ws2 = Whs[2 << 10];
            uint4 ws3 = Whs[3 << 10];

            float acc0 = xacc[tt];
            float acc1 = 0.0f;

            // register-resident W_hh: k4 = 0..15
            #pragma unroll
            for (int k4 = 0; k4 < NREG; ++k4) {
                uint4 ha = h_u4[k4];             // wave-uniform -> broadcast
                DOT4(wreg[k4], ha);
            }

            // LDS-resident W_hh: k4 = 16..24
            #pragma unroll
            for (int j = 0; j < NLDS; ++j) {
                uint4 w  = wlds[(j << 10) + tid];  // lane-consecutive b128, conflict-free
                uint4 ha = h_u4[NREG + j];
                DOT4(w, ha);
            }

            // remaining streamed loads (k4=29..31)
            uint4 ws4 = Whs[4 << 10];
            uint4 ws5 = Whs[5 << 10];
            uint4 ws6 = Whs[6 << 10];

            { uint4 ha = h_u4[25]; DOT4(ws0, ha); }
            { uint4 ha = h_u4[26]; DOT4(ws1, ha); }
            { uint4 ha = h_u4[27]; DOT4(ws2, ha); }
            { uint4 ha = h_u4[28]; DOT4(ws3, ha); }
            { uint4 ha = h_u4[29]; DOT4(ws4, ha); }
            { uint4 ha = h_u4[30]; DOT4(ws5, ha); }
            { uint4 ha = h_u4[31]; DOT4(ws6, ha); }

            g_s[tid] = acc0 + acc1;
            __syncthreads();   // bar G: gates ready

            if (tid < LSTM_H) {
                float gi = g_s[tid];
                float gf = g_s[tid + 256];
                float gg = g_s[tid + 512];
                float go = g_s[tid + 768];
                c = sigmoidf_(gf) * c + sigmoidf_(gi) * tanhf_(gg);
                hlast = sigmoidf_(go) * tanhf_(c);
                // pack h into f16 pairs: even lane combines with odd partner
                uint32_t mine = (uint32_t)__half_as_ushort(__float2half(hlast));
                uint32_t partner = (uint32_t)__shfl_xor((int)mine, 1, 64);
                if ((tid & 1) == 0) h_u[tid >> 1] = (mine & 0xffffu) | (partner << 16);
            }
            __syncthreads();   // bar H: h_{t+1} visible for next dot
        }
    }

    if (tid < LSTM_H) {
        out[b * LSTM_H + tid]                   = hlast;  // h_T
        out[LSTM_B * LSTM_H + b * LSTM_H + tid] = c;      // c_T
    }
}

extern "C" void kernel_launch(void* const* d_in, const int* in_sizes, int n_in,
                              void* d_out, int out_size, void* d_ws, size_t ws_size,
                              hipStream_t stream) {
    const float* xs   = (const float*)d_in[0];  // [64,4096,256]
    const float* W_ih = (const float*)d_in[1];  // [1024,256]
    const float* W_hh = (const float*)d_in[2];  // [1024,256]
    const float* b    = (const float*)d_in[3];  // [1024]
    float* out = (float*)d_out;
    uint32_t* Wp = (uint32_t*)d_ws;             // 1 MiB packed f16 weights

    prep_weights<<<1024, 256, 0, stream>>>(W_ih, W_hh, Wp);
    lstm_r6<<<LSTM_B, 1024, 0, stream>>>(xs, b, (const uint4*)Wp, out);
}